// Round 10
// baseline (15188.544 us; speedup 1.0000x reference)
//
#include <hip/hip_runtime.h>
#include <math.h>

#define KDIM 2560
#define DDIM 512
#define NB 64

#define QM 2560
#define QM2 1024
#define QN 512
#define PW 16
#define QACT 528   // active rows per panel: [dense 512 ; upper-tri] fill-in bound = 512+PW

// out layout (floats): m_cor @0 (2560), l_cor @2560 (2560*2560), u @6556160 (512),
// error @6556672 (512), diffusion @6557184 (1)
#define OUT_LCOR 2560
#define OUT_U    6556160
#define OUT_ERR  6556672
#define OUT_DIFF 6557184

// scal layout (doubles): [0..4]=p_pat, [5..9]=pinv_pat, [10]=diffusion

// fused: setup (block 0 writes scal; all blocks compute locally) + mext + mobs
__global__ __launch_bounds__(256) void k_mext_mobs(const float* a, const float* m0, const float* H,
                                                   const float* bias, const float* dt,
                                                   double* scal, double* mext, double* mobs){
  __shared__ double me[KDIM];
  __shared__ double red[256];
  double pp[5], pv[5];
  {
    double adt = fabs((double)dt[0]);
    const double scales5[5] = {24.0,6.0,2.0,1.0,1.0};
    #pragma unroll
    for (int i=0;i<5;i++){
      double pw = (double)(4-i)+0.5;
      pp[i]=pow(adt, pw)/scales5[i];
      pv[i]=pow(adt,-pw)*scales5[i];
    }
  }
  int tid=threadIdx.x;
  if (blockIdx.x==0 && tid==0){
    #pragma unroll
    for (int i=0;i<5;i++){ scal[i]=pp[i]; scal[5+i]=pv[i]; }
  }
  for (int r=tid; r<KDIM; r+=256){
    int j=r/5, i=r%5;
    const float* arow = a + (size_t)r*KDIM + 5*j;
    const float* m0b  = m0 + 5*j;
    double acc=0;
    #pragma unroll
    for (int l=0;l<5;l++) acc += (double)arow[l]*pv[l]*(double)m0b[l];
    me[r] = pp[i]*acc;
  }
  __syncthreads();
  if (blockIdx.x==0) for (int r=tid;r<KDIM;r+=256) mext[r]=me[r];
  int b = blockIdx.x;
  const float* Hr = H + (size_t)b*KDIM;
  double acc=0;
  for (int c=tid;c<KDIM;c+=256) acc += (double)Hr[c]*me[c];
  red[tid]=acc; __syncthreads();
  for (int s=128;s>0;s>>=1){ if (tid<s) red[tid]+=red[tid+s]; __syncthreads(); }
  if (tid==0) mobs[b] = red[0] - (double)bias[b];
}

// A = (H @ (p_inv[:,None]*q)).T  split: rows<512 -> Atop (1024-lda col-major),
// rows>=512 -> Abot (2048-lda col-major, for Gram compression)
__global__ void k_A2(const float* H, const float* q, const double* scal,
                     double* Atop, double* Abot){
  int idx = blockIdx.x*blockDim.x+threadIdx.x;
  if (idx >= QN*QM) return;
  double pv[5];
  #pragma unroll
  for (int t=0;t<5;t++) pv[t]=scal[5+t];
  int j = idx / QM;
  int i = idx % QM;
  int bi = i/5;
  double acc=0;
  #pragma unroll
  for (int t=0;t<5;t++)
    acc += (double)H[(size_t)j*QM + 5*bi+t]*pv[t]*(double)q[(size_t)(5*bi+t)*QM + i];
  if (i < 512) Atop[(size_t)j*QM2 + i] = acc;
  else         Abot[(size_t)j*2048 + (i-512)] = acc;
}

// ---- Householder QR on compressed 1024x512 (LAPACK signs) ----
// ONE launch per 16-col step: block 0 = [prologue: apply reflector set p-1 to own
// 16 cols in registers] + panel; blocks>=1 = trailing update of set p-1 on one
// column each. At p==0: block 0 reads its B rows from Gbot; blocks>=1 copy
// B cols 16..511 into AQ (fold of old k_copyB; disjoint from block 0's writes).
// Fully unrolled (runtime-indexed arrays spill — round-4 lesson).
__global__ __launch_bounds__(576) void qr_step(double* A, double* vhead, double* Tbufs,
                                               const double* Gbot, int p){
  int col0 = p*PW;
  int tid=threadIdx.x, wid=tid>>6, lane=tid&63;

  if (blockIdx.x > 0){
    if (p==0){
      // copyB: cols 16..511 of B = chol(Abot^T Abot)^T into AQ rows 512..1023
      int idx=((int)blockIdx.x-1)*576+tid;
      if (idx < 496*512){
        int c=16+idx/512, rr=idx%512;
        A[(size_t)c*QM2 + 512 + rr] = (rr<=c)? Gbot[(size_t)c*512+rr] : 0.0;
      }
      return;
    }
    int pc0 = col0 - PW;
    const double* T = Tbufs + (size_t)(p-1)*PW*PW;
    int cc = col0 + PW + ((int)blockIdx.x - 1);
    int m = QM2 - pc0; if (m>QACT) m=QACT;
    __shared__ double redu[9][PW];
    __shared__ double yshu[PW];
    __shared__ double wshu[PW];
    int lr = tid;
    double a = (lr<m)? A[(size_t)cc*QM2 + pc0 + lr] : 0.0;
    double vv[PW];
    #pragma unroll
    for (int j=0;j<PW;j++){
      double vj=0.0;
      if (lr<m){
        if (lr>j)       vj=A[(size_t)(pc0+j)*QM2 + pc0 + lr];
        else if (lr==j) vj=vhead[pc0+j];
      }
      vv[j]=vj;
    }
    #pragma unroll
    for (int j=0;j<PW;j++){
      double d=vv[j]*a;
      #pragma unroll
      for (int o=32;o>0;o>>=1) d+=__shfl_down(d,o);
      if (lane==0) redu[wid][j]=d;
    }
    __syncthreads();
    if (tid<PW){
      double y=0;
      #pragma unroll
      for (int t=0;t<9;t++) y+=redu[t][tid];
      yshu[tid]=y;
    }
    __syncthreads();
    if (tid<PW){
      double s=0;
      for (int t=0;t<=tid;t++) s+=T[t*PW+tid]*yshu[t];
      wshu[tid]=s;
    }
    __syncthreads();
    if (lr<m){
      double s=0;
      #pragma unroll
      for (int j=0;j<PW;j++) s+=vv[j]*wshu[j];
      A[(size_t)cc*QM2 + pc0 + lr]=a-s;
    }
    return;
  }

  __shared__ double redw[9][PW];
  __shared__ double rednorm[9];
  __shared__ double sh[3];
  __shared__ double wsh[PW];
  __shared__ double alphas[PW], betas[PW];
  __shared__ double VtVs[PW][PW];
  __shared__ double Tsh[PW][PW];
  __shared__ double redP[9][PW*PW];
  __shared__ double ysh2[PW][PW];
  __shared__ double wsh2[PW][PW];

  int m = QM2 - col0; if (m>QACT) m=QACT;
  bool on = tid < m;
  double x[PW];

  if (p>0){
    int pc0 = col0 - PW;
    const double* T = Tbufs + (size_t)(p-1)*PW*PW;
    int mp = QM2 - pc0; if (mp>QACT) mp=QACT;
    bool gA = on;
    bool gB = (tid>=560);
    int rowA = col0 + tid;
    int kB   = tid - 560;
    double vv[PW];
    #pragma unroll
    for (int j=0;j<PW;j++){
      double vj=0.0;
      if (gA){
        if (tid + PW < mp) vj = A[(size_t)(pc0+j)*QM2 + rowA];
      } else if (gB){
        if (kB>j)       vj=A[(size_t)(pc0+j)*QM2 + pc0 + kB];
        else if (kB==j) vj=vhead[pc0+j];
      }
      vv[j]=vj;
    }
    #pragma unroll
    for (int c=0;c<PW;c++){
      double a=0.0;
      if (gA)      a = A[(size_t)(col0+c)*QM2 + rowA];
      else if (gB) a = A[(size_t)(col0+c)*QM2 + pc0 + kB];
      x[c]=a;
    }
    #pragma unroll
    for (int c=0;c<PW;c++){
      #pragma unroll
      for (int j=0;j<PW;j++){
        double d=vv[j]*x[c];
        #pragma unroll
        for (int o=32;o>0;o>>=1) d+=__shfl_down(d,o);
        if (lane==0) redP[wid][c*PW+j]=d;
      }
    }
    __syncthreads();
    if (tid<PW*PW){
      double y=0;
      #pragma unroll
      for (int t=0;t<9;t++) y+=redP[t][tid];
      ysh2[tid>>4][tid&15]=y;
    }
    __syncthreads();
    if (tid<PW*PW){
      int c=tid>>4, jj=tid&15;
      double s=0;
      for (int t=0;t<=jj;t++) s+=T[t*PW+jj]*ysh2[c][t];
      wsh2[c][jj]=s;
    }
    __syncthreads();
    #pragma unroll
    for (int c=0;c<PW;c++){
      double s=0;
      #pragma unroll
      for (int j=0;j<PW;j++) s+=vv[j]*wsh2[c][j];
      x[c]-=s;
    }
    if (gB){
      #pragma unroll
      for (int c=0;c<PW;c++) A[(size_t)(col0+c)*QM2 + pc0 + kB] = x[c];
    }
    if (!on){
      #pragma unroll
      for (int c=0;c<PW;c++) x[c]=0.0;
    }
    __syncthreads();
  } else {
    // p==0: rows <512 from Atop region of AQ; rows 512..527 direct from Gbot
    #pragma unroll
    for (int j=0;j<PW;j++){
      double v=0.0;
      if (tid<512) v = A[(size_t)j*QM2 + tid];
      else if (tid<QACT){
        int rr=tid-512;
        v = (rr<=j)? Gbot[(size_t)j*512+rr] : 0.0;
      }
      x[j]=v;
    }
  }

  #pragma unroll
  for (int j=0;j<PW;j++){
    double v0 = (tid>=j && on)? x[j] : 0.0;
    double ps = v0*v0;
    #pragma unroll
    for (int o=32;o>0;o>>=1) ps += __shfl_down(ps,o);
    if (lane==0) rednorm[wid]=ps;
    if (tid==j) sh[0]=x[j];
    __syncthreads();
    if (tid==0){
      double s0=0;
      for (int t=0;t<9;t++) s0+=rednorm[t];
      double x1=sh[0];
      double nrm=sqrt(s0);
      double alpha=(x1>=0.0)?-nrm:nrm;     // LAPACK: R_cc = -sign(x1)*||x||
      double v1=x1-alpha;
      double vtv=s0-2.0*alpha*x1+alpha*alpha;
      double b=(vtv>0.0)?2.0/vtv:0.0;
      sh[1]=v1; sh[2]=b;
      alphas[j]=alpha; betas[j]=b;
      vhead[col0+j]=v1;
    }
    __syncthreads();
    if (tid==j) x[j]=sh[1];
    double b=sh[2];
    double v=(tid>=j && on)? x[j] : 0.0;
    #pragma unroll
    for (int t=0;t<PW;t++){
      if (t==j) continue;
      double pdot=v*x[t];
      #pragma unroll
      for (int o=32;o>0;o>>=1) pdot+=__shfl_down(pdot,o);
      if (lane==0) redw[wid][t]=pdot;
    }
    __syncthreads();
    if (tid<PW && tid!=j){
      double tot=0;
      #pragma unroll
      for (int t2=0;t2<9;t2++) tot+=redw[t2][tid];
      if (tid>j) wsh[tid]=b*tot;
      else       VtVs[tid][j]=tot;
    }
    __syncthreads();
    if (v!=0.0){
      #pragma unroll
      for (int t=j+1;t<PW;t++) x[t]-=wsh[t]*v;
    }
  }
  __syncthreads();
  if (tid<PW){
    int i=tid;
    Tsh[i][i]=betas[i];
    for (int j2=i+1;j2<PW;j2++){
      double z=0;
      for (int t=i;t<j2;t++) z+=Tsh[i][t]*VtVs[t][j2];
      Tsh[i][j2]=-betas[j2]*z;
    }
  }
  __syncthreads();
  for (int e=tid;e<PW*PW;e+=576){
    int i=e/PW, j2=e%PW;
    Tbufs[(size_t)p*PW*PW + e] = (j2>=i)? Tsh[i][j2] : 0.0;
  }
  if (on){
    #pragma unroll
    for (int j=0;j<PW;j++)
      A[(size_t)(col0+j)*QM2 + col0 + tid] = (tid==j)? alphas[j] : x[j];
  }
}

// fused: R column norms + backward solve R x = m_obs + diffusion + error (R in AQ, lda QM2)
__global__ __launch_bounds__(512) void k_rpost(const double* Aq, const double* mobs,
                                               double* scal, float* out){
  __shared__ double b[DDIM];
  __shared__ double xs[DDIM];
  __shared__ double D[NB][NB+1];
  __shared__ double red[DDIM];
  __shared__ double g1sh[DDIM];
  int tid=threadIdx.x;
  {
    double s=0;
    for (int r=0;r<=tid;r++){ double v=Aq[(size_t)tid*QM2 + r]; s+=v*v; }
    g1sh[tid]=s;
  }
  b[tid]=mobs[tid];
  __syncthreads();
  for (int p=7;p>=0;p--){
    int b0=p*NB;
    for (int e=tid;e<NB*NB;e+=512){ int i=e&63, j2=e>>6; D[i][j2]=Aq[(size_t)(b0+j2)*QM2 + b0+i]; }
    __syncthreads();
    if (tid<64){
      double bi=b[b0+tid];
      for (int k=NB-1;k>=0;k--){
        double bk=__shfl(bi,k);
        double xk=bk/D[k][k];
        if (tid<k) bi-=D[tid][k]*xk;
        if (tid==k) bi=xk;
      }
      xs[b0+tid]=bi;
    }
    __syncthreads();
    if (tid<b0){
      double s=0;
      #pragma unroll 8
      for (int j2=0;j2<NB;j2++) s+=Aq[(size_t)(b0+j2)*QM2 + tid]*xs[b0+j2];
      b[tid]-=s;
    }
    __syncthreads();
  }
  red[tid]=xs[tid]*xs[tid]; __syncthreads();
  for (int s=256;s>0;s>>=1){ if (tid<s) red[tid]+=red[tid+s]; __syncthreads(); }
  double diff=sqrt(red[0]/(double)DDIM);
  if (tid==0){ scal[10]=diff; out[OUT_DIFF]=(float)diff; }
  out[OUT_ERR+tid]=(float)(diff*sqrt(fmax(g1sh[tid],0.0)));
}

// X = a @ (p_inv[:,None]*l0)
__global__ void k_X(const float* a, const float* l0, const double* scal, float* X){
  int idx=blockIdx.x*blockDim.x+threadIdx.x;
  if (idx>=KDIM*KDIM) return;
  double pv[5];
  #pragma unroll
  for (int t=0;t<5;t++) pv[t]=scal[5+t];
  int r=idx/KDIM, c=idx%KDIM;
  int j=r/5;
  const float* arow = a + (size_t)r*KDIM + 5*j;
  double acc=0;
  #pragma unroll
  for (int l=0;l<5;l++)
    acc += (double)arow[l]*pv[l]*(double)l0[(size_t)(5*j+l)*KDIM+c];
  X[idx]=(float)acc;
}

// ---- 32x32-tile GEMM, 2x2 per thread, fp64 accumulate ----
template<typename TA,int ATR,typename TB,int BTR,int MODE>
__global__ __launch_bounds__(256) void gemm32(const TA* __restrict__ A,int lda,
                                              const TB* __restrict__ B,int ldb,
                                              void* __restrict__ Cv,int ldc,
                                              int K,int kmode){
  __shared__ double As[32][33];
  __shared__ double Bs[32][33];
  int tid=threadIdx.x, tx=tid&15, ty=tid>>4;
  int n0=blockIdx.x*32, m0=blockIdx.y*32;
  int ks=0, ke=K;
  if (kmode==1) ks=n0;
  else if (kmode==2) ke=min(K,n0+32);
  else if (kmode==3) ke=min(K,m0+32);
  else if (kmode==4) ks=m0;
  double acc[2][2]={};
  for (int k0=ks;k0<ke;k0+=32){
    if (ATR){
      for (int e=tid;e<32*32;e+=256){int k=e>>5,mm=e&31; As[k][mm]=(double)A[(size_t)(k0+k)*lda+m0+mm];}
    } else {
      for (int e=tid;e<32*32;e+=256){int mm=e>>5,k=e&31; As[k][mm]=(double)A[(size_t)(m0+mm)*lda+k0+k];}
    }
    if (BTR){
      for (int e=tid;e<32*32;e+=256){int nn=e>>5,k=e&31; Bs[k][nn]=(double)B[(size_t)(n0+nn)*ldb+k0+k];}
    } else {
      for (int e=tid;e<32*32;e+=256){int k=e>>5,nn=e&31; Bs[k][nn]=(double)B[(size_t)(k0+k)*ldb+n0+nn];}
    }
    __syncthreads();
    #pragma unroll
    for (int t=0;t<32;t++){
      double av[2],bv[2];
      #pragma unroll
      for (int i=0;i<2;i++){av[i]=As[t][ty+16*i];bv[i]=Bs[t][tx+16*i];}
      #pragma unroll
      for (int i=0;i<2;i++)
        #pragma unroll
        for (int j=0;j<2;j++) acc[i][j]+=av[i]*bv[j];
    }
    __syncthreads();
  }
  #pragma unroll
  for (int i=0;i<2;i++){
    #pragma unroll
    for (int j=0;j<2;j++){
      size_t idx=(size_t)(m0+ty+16*i)*ldc+n0+tx+16*j;
      if (MODE==0) ((double*)Cv)[idx]=acc[i][j];
      else if (MODE==1) ((double*)Cv)[idx]-=acc[i][j];
      else ((float*)Cv)[idx]=(float)acc[i][j];
    }
  }
}

// G (lower tiles) = X X^T (band-limited) + fused diffusion^2 * kron(I, L1 L1^T)
// 1-D triangular grid, longest-K first; float4 staging, K-chunk 32 (halved syncs)
__global__ __launch_bounds__(256) void syrk_lower(const float* __restrict__ X, const float* __restrict__ q,
                                                  const double* __restrict__ scal,
                                                  double* __restrict__ G, int n){
  int t = blockIdx.x;
  int u = (int)((sqrtf(8.0f*(float)t+1.0f)+1.0f)*0.5f);
  while ((u*(u-1))/2 > t) u--;
  while ((u*(u+1))/2 <= t) u++;
  int s = (KDIM/64) - u;
  int r = s + (t - (u*(u-1))/2);
  int S0=s*64, R0=r*64;
  __shared__ double As[32][65];
  __shared__ double Bs[32][65];
  int tid=threadIdx.x, tx=tid&15, ty=tid>>4;
  int kend=min(n, S0+80);
  double acc[4][4]={};
  int mm=tid>>2, f=tid&3;
  for (int k0=0;k0<kend;k0+=32){
    {
      float4 xa = *(const float4*)(X + (size_t)(R0+mm)*n + k0 + 4*f);
      float4 xb = *(const float4*)(X + (size_t)(S0+mm)*n + k0 + 4*f);
      As[4*f+0][mm]=(double)xa.x; As[4*f+1][mm]=(double)xa.y;
      As[4*f+2][mm]=(double)xa.z; As[4*f+3][mm]=(double)xa.w;
      Bs[4*f+0][mm]=(double)xb.x; Bs[4*f+1][mm]=(double)xb.y;
      Bs[4*f+2][mm]=(double)xb.z; Bs[4*f+3][mm]=(double)xb.w;
      if (k0+16 < kend){
        float4 ya = *(const float4*)(X + (size_t)(R0+mm)*n + k0 + 16 + 4*f);
        float4 yb = *(const float4*)(X + (size_t)(S0+mm)*n + k0 + 16 + 4*f);
        As[16+4*f+0][mm]=(double)ya.x; As[16+4*f+1][mm]=(double)ya.y;
        As[16+4*f+2][mm]=(double)ya.z; As[16+4*f+3][mm]=(double)ya.w;
        Bs[16+4*f+0][mm]=(double)yb.x; Bs[16+4*f+1][mm]=(double)yb.y;
        Bs[16+4*f+2][mm]=(double)yb.z; Bs[16+4*f+3][mm]=(double)yb.w;
      } else {
        #pragma unroll
        for (int i=0;i<4;i++){ As[16+4*f+i][mm]=0.0; Bs[16+4*f+i][mm]=0.0; }
      }
    }
    __syncthreads();
    #pragma unroll
    for (int t2=0;t2<32;t2++){
      double av[4],bv[4];
      #pragma unroll
      for (int i=0;i<4;i++){av[i]=As[t2][ty+16*i];bv[i]=Bs[t2][tx+16*i];}
      #pragma unroll
      for (int i=0;i<4;i++)
        #pragma unroll
        for (int j=0;j<4;j++) acc[i][j]+=av[i]*bv[j];
    }
    __syncthreads();
  }
  double dd = scal[10]*scal[10];
  #pragma unroll
  for (int i=0;i<4;i++)
    #pragma unroll
    for (int j=0;j<4;j++){
      int rr=R0+ty+16*i, c=S0+tx+16*j;
      double v=acc[i][j];
      if (c<=rr && (rr/5)==(c/5)){
        double qq=0;
        #pragma unroll
        for (int k=0;k<5;k++) qq += (double)q[(size_t)(rr%5)*KDIM+k]*(double)q[(size_t)(c%5)*KDIM+k];
        v += dd*qq;
      }
      G[(size_t)rr*n+c]=v;
    }
}

// ---- blocked Cholesky ----
__global__ __launch_bounds__(256) void chol_diag(double* A, int n, int k0){
  __shared__ double P[NB][NB+1];
  int tid=threadIdx.x;
  for (int e=tid;e<NB*NB;e+=256){int r=e>>6,c=e&63;P[r][c]=A[(size_t)(k0+r)*n+k0+c];}
  int tx=tid&15, ty=tid>>4;
  __syncthreads();
  for (int j=0;j<NB;j++){
    double pj=P[j][j];
    __syncthreads();
    double rpj=1.0/sqrt(fmax(pj,1e-280));
    if (tid>j && tid<NB) P[tid][j]*=rpj;
    if (tid==j) P[j][j]=sqrt(fmax(pj,1e-280));
    __syncthreads();
    #pragma unroll
    for (int a2=0;a2<4;a2++){
      int r=ty+16*a2;
      double lrj=P[r][j];
      #pragma unroll
      for (int b2=0;b2<4;b2++){
        int c=tx+16*b2;
        if (r>j && c>j && c<=r) P[r][c]-=lrj*P[c][j];
      }
    }
    __syncthreads();
  }
  for (int e=tid;e<NB*NB;e+=256){int r=e>>6,c=e&63;A[(size_t)(k0+r)*n+k0+c]=P[r][c];}
}

// ONE launch per elimination step: each block locally re-solves its two panel
// tiles vs L_D (forward substitution — identical to trsm output),
// updates trailing tile (r,s); tile 0 fuses next-diag factorization.
__global__ __launch_bounds__(256) void chol_step(double* __restrict__ A, int n, int k0){
  __shared__ double Ls[NB][NB+1];   // L_D; reused as P by tile 0
  __shared__ double rec[NB];
  __shared__ double As[16][65];
  __shared__ double Bs[16][65];
  int ts0=k0+NB;
  int t=blockIdx.x;
  int r=(int)((sqrtf(8.0f*(float)t+1.0f)-1.0f)*0.5f);
  while ((r*(r+1))/2 > t) r--;
  while (((r+1)*(r+2))/2 <= t) r++;
  int s=t-(r*(r+1))/2;
  int R0=ts0+r*NB, S0=ts0+s*NB;
  int tid=threadIdx.x, tx=tid&15, ty=tid>>4;
  for (int e=tid;e<NB*NB;e+=256){int rr=e>>6,c=e&63;Ls[rr][c]=A[(size_t)(k0+rr)*n+k0+c];}
  __syncthreads();
  if (tid<NB) rec[tid]=1.0/Ls[tid][tid];
  __syncthreads();
  double ar[NB];
  bool solver = (tid<64) || (tid<128 && s!=r);
  int srow = (tid<64)? (R0+tid) : (S0+(tid-64));
  if (solver){
    #pragma unroll
    for (int c=0;c<NB;c++) ar[c]=A[(size_t)srow*n + k0 + c];
    #pragma unroll
    for (int j=0;j<NB;j++){
      double sv=ar[j];
      #pragma unroll
      for (int t2=0;t2<j;t2++) sv-=ar[t2]*Ls[j][t2];
      ar[j]=sv*rec[j];
    }
  }
  double acc[4][4]={};
  #pragma unroll
  for (int c4=0;c4<4;c4++){
    __syncthreads();
    if (tid<64){
      #pragma unroll
      for (int k=0;k<16;k++) As[k][tid]=ar[c4*16+k];
      if (s==r){
        #pragma unroll
        for (int k=0;k<16;k++) Bs[k][tid]=ar[c4*16+k];
      }
    } else if (tid<128 && s!=r){
      #pragma unroll
      for (int k=0;k<16;k++) Bs[k][tid-64]=ar[c4*16+k];
    }
    __syncthreads();
    #pragma unroll
    for (int tt=0;tt<16;tt++){
      double av[4],bv[4];
      #pragma unroll
      for (int i=0;i<4;i++){av[i]=As[tt][ty+16*i];bv[i]=Bs[tt][tx+16*i];}
      #pragma unroll
      for (int i=0;i<4;i++)
        #pragma unroll
        for (int j=0;j<4;j++) acc[i][j]+=av[i]*bv[j];
    }
  }
  __syncthreads();
  if (t!=0){
    #pragma unroll
    for (int i=0;i<4;i++)
      #pragma unroll
      for (int j=0;j<4;j++)
        A[(size_t)(R0+ty+16*i)*n+S0+tx+16*j]-=acc[i][j];
    return;
  }
  double (*P)[NB+1] = Ls;
  #pragma unroll
  for (int i=0;i<4;i++)
    #pragma unroll
    for (int j=0;j<4;j++)
      P[ty+16*i][tx+16*j] = A[(size_t)(ts0+ty+16*i)*n+ts0+tx+16*j] - acc[i][j];
  __syncthreads();
  for (int j=0;j<NB;j++){
    double pj=P[j][j];
    __syncthreads();
    double rpj=1.0/sqrt(fmax(pj,1e-280));
    if (tid>j && tid<NB) P[tid][j]*=rpj;
    if (tid==j) P[j][j]=sqrt(fmax(pj,1e-280));
    __syncthreads();
    #pragma unroll
    for (int a2=0;a2<4;a2++){
      int r2=ty+16*a2;
      double lrj=P[r2][j];
      #pragma unroll
      for (int b2=0;b2<4;b2++){
        int c=tx+16*b2;
        if (r2>j && c>j && c<=r2) P[r2][c]-=lrj*P[c][j];
      }
    }
    __syncthreads();
  }
  for (int e=tid;e<NB*NB;e+=256){int r2=e>>6,c=e&63;A[(size_t)(ts0+r2)*n+ts0+c]=P[r2][c];}
}

// final sweep: trsm ALL raw panels vs their factored diagonals in ONE launch.
__global__ __launch_bounds__(256) void chol_sweep(double* A, int n){
  __shared__ double Ls[NB][NB+1];
  __shared__ double St[NB][NB+1];
  __shared__ double rec[NB];
  int k0=blockIdx.y*NB;
  int base=k0+NB+blockIdx.x*256;
  if (base>=n) return;
  int tid=threadIdx.x;
  for (int e=tid;e<NB*NB;e+=256){int r2=e>>6,c=e&63;Ls[r2][c]=A[(size_t)(k0+r2)*n+k0+c];}
  __syncthreads();
  if (tid<NB) rec[tid]=1.0/Ls[tid][tid];
  int myrow=base+tid, mychunk=tid>>6, lrow=tid&63;
  double ar[NB];
  for (int ch=0;ch<4;ch++){
    int r0=base+ch*64;
    for (int e=tid;e<NB*NB;e+=256){
      int r2=e>>6,c=e&63;
      if (r0+r2<n) St[r2][c]=A[(size_t)(r0+r2)*n+k0+c];
    }
    __syncthreads();
    if (mychunk==ch && myrow<n){
      #pragma unroll
      for (int c=0;c<NB;c++) ar[c]=St[lrow][c];
    }
    __syncthreads();
  }
  if (myrow<n){
    #pragma unroll
    for (int j=0;j<NB;j++){
      double s2=ar[j];
      #pragma unroll
      for (int t2=0;t2<j;t2++) s2-=ar[t2]*Ls[j][t2];
      ar[j]=s2*rec[j];
    }
  }
  for (int ch=0;ch<4;ch++){
    int r0=base+ch*64;
    if (mychunk==ch && myrow<n){
      #pragma unroll
      for (int c=0;c<NB;c++) St[lrow][c]=ar[c];
    }
    __syncthreads();
    for (int e=tid;e<NB*NB;e+=256){
      int r2=e>>6,c=e&63;
      if (r0+r2<n) A[(size_t)(r0+r2)*n+k0+c]=St[r2][c];
    }
    __syncthreads();
  }
}

// l_ext (f32) = p[:,None] * chol(G2), zero strict upper
__global__ void k_extract(const double* G2, const double* scal, float* lext){
  int idx=blockIdx.x*blockDim.x+threadIdx.x;
  if (idx>=KDIM*KDIM) return;
  int r=idx/KDIM, c=idx%KDIM;
  double v = (c<=r)? scal[r%5]*G2[idx] : 0.0;
  lext[idx]=(float)v;
}

// ---- inverse of lower-triangular L (512): diag inverses then one-launch strips ----
__global__ __launch_bounds__(256) void trinv_diag(const double* S, double* Linv){
  __shared__ double Ls[NB][NB+1];
  __shared__ double Ti[NB][NB+1];
  int jb=blockIdx.x, tid=threadIdx.x;
  for (int e=tid; e<DDIM*NB; e+=256){
    int r=e/NB, c=e%NB;
    Linv[(size_t)r*DDIM + jb*NB + c]=0.0;
  }
  for (int e=tid;e<NB*NB;e+=256){int r=e>>6,c=e&63; Ls[r][c]=S[(size_t)(jb*NB+r)*DDIM + jb*NB+c];}
  __syncthreads();
  if (tid<NB){
    int c=tid;
    for (int r=c;r<NB;r++){
      double s=(r==c)?1.0:0.0;
      for (int t=c;t<r;t++) s-=Ls[r][t]*Ti[t][c];
      Ti[r][c]=s/Ls[r][r];
    }
    for (int r=0;r<c;r++) Ti[r][c]=0.0;
  }
  __syncthreads();
  for (int e=tid;e<NB*NB;e+=256){int r=e>>6,c=e&63; Linv[(size_t)(jb*NB+r)*DDIM + jb*NB+c]=Ti[r][c];}
}

// block jb computes block-column jb of Linv top-down (reads only its own prior
// writes + the diag inverses from trinv_diag). ONE launch replaces 7 trinv_steps.
__global__ __launch_bounds__(256) void trinv_all(const double* S, double* Linv){
  __shared__ double As[16][65];
  __shared__ double Bs[16][65];
  __shared__ double Ps[NB][NB+1];
  int jb=blockIdx.x;
  int tid=threadIdx.x, tx=tid&15, ty=tid>>4;
  for (int ib=jb+1; ib<8; ib++){
    double acc[4][4]={};
    int kstart=jb*NB, kend=ib*NB;
    for (int k0=kstart;k0<kend;k0+=16){
      for (int e=tid;e<64*16;e+=256){int mm=e>>4,k=e&15; As[k][mm]=S[(size_t)(ib*NB+mm)*DDIM + k0+k];}
      for (int e=tid;e<16*64;e+=256){int k=e>>6,nn=e&63; Bs[k][nn]=Linv[(size_t)(k0+k)*DDIM + jb*NB+nn];}
      __syncthreads();
      #pragma unroll
      for (int t=0;t<16;t++){
        double av[4],bv[4];
        #pragma unroll
        for (int i=0;i<4;i++){av[i]=As[t][ty+16*i];bv[i]=Bs[t][tx+16*i];}
        #pragma unroll
        for (int i=0;i<4;i++)
          #pragma unroll
          for (int j=0;j<4;j++) acc[i][j]+=av[i]*bv[j];
      }
      __syncthreads();
    }
    #pragma unroll
    for (int i=0;i<4;i++)
      #pragma unroll
      for (int j=0;j<4;j++) Ps[ty+16*i][tx+16*j]=acc[i][j];
    double o[4][4]={};
    __syncthreads();
    for (int k0=0;k0<NB;k0+=16){
      for (int e=tid;e<64*16;e+=256){int mm=e>>4,k=e&15; As[k][mm]=Linv[(size_t)(ib*NB+mm)*DDIM + ib*NB+k0+k];}
      __syncthreads();
      #pragma unroll
      for (int t=0;t<16;t++){
        double av[4],bv[4];
        #pragma unroll
        for (int i=0;i<4;i++){av[i]=As[t][ty+16*i];bv[i]=Ps[k0+t][tx+16*i];}
        #pragma unroll
        for (int i=0;i<4;i++)
          #pragma unroll
          for (int j=0;j<4;j++) o[i][j]+=av[i]*bv[j];
      }
      __syncthreads();
    }
    #pragma unroll
    for (int i=0;i<4;i++)
      #pragma unroll
      for (int j=0;j<4;j++)
        Linv[(size_t)(ib*NB+ty+16*i)*DDIM + jb*NB+tx+16*j] = -o[i][j];
    __syncthreads();   // global write visibility for next ib's Bs staging
  }
}

// m_cor = m_ext - Z^T @ m_obs; also u
__global__ void k_mcor(const double* Z, const double* mobs, const double* mext, float* out){
  __shared__ double mo[DDIM];
  for (int s=threadIdx.x;s<DDIM;s+=256) mo[s]=mobs[s];
  __syncthreads();
  int r=blockIdx.x*256+threadIdx.x;
  if (r>=KDIM) return;
  double acc=0;
  for (int s=0;s<DDIM;s++) acc += Z[(size_t)s*KDIM+r]*mo[s];
  double mc = mext[r]-acc;
  out[r]=(float)mc;
  if (r%5==0) out[OUT_U + r/5]=(float)mc;
}

// l_cor = l_ext - Z^T @ l_obs_ns (64x64 tiles); float4 staging for lobs
__global__ __launch_bounds__(256) void k_lcor(const double* __restrict__ Z, const float* __restrict__ lobs,
                                              const float* __restrict__ lext, float* __restrict__ out){
  __shared__ double As[16][65];
  __shared__ double Bs[16][65];
  int tid=threadIdx.x, tx=tid&15, ty=tid>>4;
  int n0=blockIdx.x*64, m0=blockIdx.y*64;
  double acc[4][4]={};
  int kk=tid>>4, f=tid&15;
  for (int k0=0;k0<DDIM;k0+=16){
    for (int e=tid;e<16*64;e+=256){int k=e>>6,mm=e&63; As[k][mm]=Z[(size_t)(k0+k)*KDIM+m0+mm];}
    {
      float4 xb = *(const float4*)(lobs + (size_t)(k0+kk)*KDIM + n0 + 4*f);
      Bs[kk][4*f+0]=(double)xb.x; Bs[kk][4*f+1]=(double)xb.y;
      Bs[kk][4*f+2]=(double)xb.z; Bs[kk][4*f+3]=(double)xb.w;
    }
    __syncthreads();
    #pragma unroll
    for (int t=0;t<16;t++){
      double av[4],bv[4];
      #pragma unroll
      for (int i=0;i<4;i++){av[i]=As[t][ty+16*i];bv[i]=Bs[t][tx+16*i];}
      #pragma unroll
      for (int i=0;i<4;i++)
        #pragma unroll
        for (int j=0;j<4;j++) acc[i][j]+=av[i]*bv[j];
    }
    __syncthreads();
  }
  #pragma unroll
  for (int i=0;i<4;i++)
    #pragma unroll
    for (int j=0;j<4;j++){
      size_t idx=(size_t)(m0+ty+16*i)*KDIM+n0+tx+16*j;
      out[OUT_LCOR+idx]=(float)((double)lext[idx]-acc[i][j]);
    }
}

extern "C" void kernel_launch(void* const* d_in, const int* in_sizes, int n_in,
                              void* d_out, int out_size, void* d_ws, size_t ws_size,
                              hipStream_t stream) {
  const float* m0  = (const float*)d_in[0];
  const float* l0  = (const float*)d_in[1];
  const float* H   = (const float*)d_in[2];
  const float* bias= (const float*)d_in[3];
  const float* dt  = (const float*)d_in[4];
  const float* a   = (const float*)d_in[5];
  const float* q   = (const float*)d_in[6];
  float* out = (float*)d_out;

  char* w=(char*)d_ws;
  auto alloc=[&](size_t bytes)->char*{ char* p=w; w += ((bytes+255)/256)*256; return p; };
  double* scal  =(double*)alloc(16*8);
  double* mext  =(double*)alloc((size_t)KDIM*8);
  double* mobs  =(double*)alloc((size_t)DDIM*8);
  double* vheadA=(double*)alloc((size_t)QN*8);
  double* Tbufs =(double*)alloc((size_t)(QN/PW)*PW*PW*8);  // per-step T factors
  double* AQ    =(double*)alloc((size_t)QM2*QN*8);    // compressed QR matrix (1024x512 col-major)
  double* S     =(double*)alloc((size_t)DDIM*DDIM*8); // innovation Gram + chol
  double* G2    =(double*)alloc((size_t)KDIM*KDIM*8); // big Gram -> chol; region reused
  float*  LOBS  =(float*) alloc((size_t)DDIM*KDIM*4);
  float*  X     =(float*) alloc((size_t)KDIM*KDIM*4); // X; later l_ext
  float*  LEXT  = X;
  // G2 region used as scratch BEFORE syrk_lower (QR compression):
  double* Abot  = G2;                                  // 2048x512 col-major
  double* Gbot  = Abot + (size_t)2048*512;             // 512x512
  // after k_extract, G2 region reused again:
  double* Linv  = G2;                                  // 512x512
  double* C2    = Linv + (size_t)DDIM*DDIM;            // 512x2560
  double* Y     = C2   + (size_t)DDIM*KDIM;            // 512x2560
  double* Z     = Y    + (size_t)DDIM*KDIM;            // 512x2560

  // Cholesky: diag0 + 1 fused launch per step + one parallel panel sweep
  auto chol_full=[&](double* M, int n){
    chol_diag<<<1,256,0,stream>>>(M, n, 0);
    for (int k0=0;k0+NB<n;k0+=NB){
      int T = (n-k0-NB)/NB;
      chol_step<<<T*(T+1)/2,256,0,stream>>>(M,n,k0);
    }
    dim3 g((n-NB+255)/256, n/NB-1);
    chol_sweep<<<g,256,0,stream>>>(M,n);
  };

  // ---- setup + extrapolate mean + observe (k_setup folded in) ----
  k_mext_mobs<<<DDIM,256,0,stream>>>(a, m0, H, bias, dt, scal, mext, mobs);

  // ---- first QR, compressed: A'' = [A_top(512); chol(A_bot^T A_bot)^T] (R identical, signs incl.)
  k_A2<<<(QN*QM+255)/256,256,0,stream>>>(H, q, scal, AQ, Abot);
  gemm32<double,0,double,1,0><<<dim3(16,16),256,0,stream>>>(Abot,2048, Abot,2048, Gbot,512, 2048, 0);
  chol_full(Gbot, 512);
  for (int p=0;p<QN/PW;p++){
    int grid;
    if (p==0) grid = 1 + (496*512 + 575)/576;   // block0=panel; rest copy B cols 16..511
    else      grid = 1 + (QN - (p+1)*PW);
    qr_step<<<grid,576,0,stream>>>(AQ, vheadA, Tbufs, Gbot, p);
  }
  k_rpost<<<1,512,0,stream>>>(AQ, mobs, scal, out);

  // ---- extrapolated covariance sqrt via Gram + Cholesky ----
  k_X<<<(KDIM*KDIM+255)/256,256,0,stream>>>(a, l0, scal, X);
  syrk_lower<<<(KDIM/64)*((KDIM/64)+1)/2,256,0,stream>>>(X, q, scal, G2, KDIM);
  chol_full(G2, KDIM);
  k_extract<<<(KDIM*KDIM+255)/256,256,0,stream>>>(G2, scal, LEXT);  // G2 dead afterwards

  // ---- correction ----
  gemm32<float,0,float,0,2><<<dim3(KDIM/32,DDIM/32),256,0,stream>>>(H,KDIM, LEXT,KDIM, LOBS,KDIM, KDIM, 1);
  gemm32<float,0,float,1,0><<<dim3(DDIM/32,DDIM/32),256,0,stream>>>(LOBS,KDIM, LOBS,KDIM, S,DDIM, KDIM, 0);
  chol_full(S, DDIM);
  trinv_diag<<<8,256,0,stream>>>(S, Linv);
  trinv_all<<<8,256,0,stream>>>(S, Linv);
  gemm32<float,0,float,1,0><<<dim3(KDIM/32,DDIM/32),256,0,stream>>>(LOBS,KDIM, LEXT,KDIM, C2,KDIM, KDIM, 2);
  gemm32<double,0,double,0,0><<<dim3(KDIM/32,DDIM/32),256,0,stream>>>(Linv,DDIM, C2,KDIM, Y,KDIM, DDIM, 3);
  gemm32<double,1,double,0,0><<<dim3(KDIM/32,DDIM/32),256,0,stream>>>(Linv,DDIM, Y,KDIM, Z,KDIM, DDIM, 4);

  k_mcor<<<(KDIM+255)/256,256,0,stream>>>(Z, mobs, mext, out);
  k_lcor<<<dim3(KDIM/64,KDIM/64),256,0,stream>>>(Z, LOBS, LEXT, out);
}

// Round 11
// 14855.719 us; speedup vs baseline: 1.0224x; 1.0224x over previous
//
#include <hip/hip_runtime.h>
#include <math.h>

#define KDIM 2560
#define DDIM 512
#define NB 64

#define QM 2560
#define QM2 1024
#define QN 512
#define PW 16
#define QACT 528   // active rows per panel: [dense 512 ; upper-tri] fill-in bound = 512+PW

// out layout (floats): m_cor @0 (2560), l_cor @2560 (2560*2560), u @6556160 (512),
// error @6556672 (512), diffusion @6557184 (1)
#define OUT_LCOR 2560
#define OUT_U    6556160
#define OUT_ERR  6556672
#define OUT_DIFF 6557184

// scal layout (doubles): [0..4]=p_pat, [5..9]=pinv_pat, [10]=diffusion

// fused: setup (block 0 writes scal; all blocks compute locally) + mext + mobs
__global__ __launch_bounds__(256) void k_mext_mobs(const float* a, const float* m0, const float* H,
                                                   const float* bias, const float* dt,
                                                   double* scal, double* mext, double* mobs){
  __shared__ double me[KDIM];
  __shared__ double red[256];
  double pp[5], pv[5];
  {
    double adt = fabs((double)dt[0]);
    const double scales5[5] = {24.0,6.0,2.0,1.0,1.0};
    #pragma unroll
    for (int i=0;i<5;i++){
      double pw = (double)(4-i)+0.5;
      pp[i]=pow(adt, pw)/scales5[i];
      pv[i]=pow(adt,-pw)*scales5[i];
    }
  }
  int tid=threadIdx.x;
  if (blockIdx.x==0 && tid==0){
    #pragma unroll
    for (int i=0;i<5;i++){ scal[i]=pp[i]; scal[5+i]=pv[i]; }
  }
  for (int r=tid; r<KDIM; r+=256){
    int j=r/5, i=r%5;
    const float* arow = a + (size_t)r*KDIM + 5*j;
    const float* m0b  = m0 + 5*j;
    double acc=0;
    #pragma unroll
    for (int l=0;l<5;l++) acc += (double)arow[l]*pv[l]*(double)m0b[l];
    me[r] = pp[i]*acc;
  }
  __syncthreads();
  if (blockIdx.x==0) for (int r=tid;r<KDIM;r+=256) mext[r]=me[r];
  int b = blockIdx.x;
  const float* Hr = H + (size_t)b*KDIM;
  double acc=0;
  for (int c=tid;c<KDIM;c+=256) acc += (double)Hr[c]*me[c];
  red[tid]=acc; __syncthreads();
  for (int s=128;s>0;s>>=1){ if (tid<s) red[tid]+=red[tid+s]; __syncthreads(); }
  if (tid==0) mobs[b] = red[0] - (double)bias[b];
}

// A = (H @ (p_inv[:,None]*q)).T  split: rows<512 -> Atop (1024-lda col-major),
// rows>=512 -> Abot (2048-lda col-major, for Gram compression)
__global__ void k_A2(const float* H, const float* q, const double* scal,
                     double* Atop, double* Abot){
  int idx = blockIdx.x*blockDim.x+threadIdx.x;
  if (idx >= QN*QM) return;
  double pv[5];
  #pragma unroll
  for (int t=0;t<5;t++) pv[t]=scal[5+t];
  int j = idx / QM;
  int i = idx % QM;
  int bi = i/5;
  double acc=0;
  #pragma unroll
  for (int t=0;t<5;t++)
    acc += (double)H[(size_t)j*QM + 5*bi+t]*pv[t]*(double)q[(size_t)(5*bi+t)*QM + i];
  if (i < 512) Atop[(size_t)j*QM2 + i] = acc;
  else         Abot[(size_t)j*2048 + (i-512)] = acc;
}

// ---- Householder QR on compressed 1024x512 (LAPACK signs) ----
// ONE launch per 16-col step: block 0 = [prologue: apply reflector set p-1 to own
// 16 cols in registers] + panel; blocks>=1 = trailing update of set p-1 on one
// column each. At p==0: block 0 reads its B rows from Gbot; blocks>=1 copy
// B cols 16..511 into AQ (fold of old k_copyB; disjoint from block 0's writes).
// Fully unrolled (runtime-indexed arrays spill — round-4 lesson).
__global__ __launch_bounds__(576) void qr_step(double* A, double* vhead, double* Tbufs,
                                               const double* Gbot, int p){
  int col0 = p*PW;
  int tid=threadIdx.x, wid=tid>>6, lane=tid&63;

  if (blockIdx.x > 0){
    if (p==0){
      // copyB: cols 16..511 of B = chol(Abot^T Abot)^T into AQ rows 512..1023
      int idx=((int)blockIdx.x-1)*576+tid;
      if (idx < 496*512){
        int c=16+idx/512, rr=idx%512;
        A[(size_t)c*QM2 + 512 + rr] = (rr<=c)? Gbot[(size_t)c*512+rr] : 0.0;
      }
      return;
    }
    int pc0 = col0 - PW;
    const double* T = Tbufs + (size_t)(p-1)*PW*PW;
    int cc = col0 + PW + ((int)blockIdx.x - 1);
    int m = QM2 - pc0; if (m>QACT) m=QACT;
    __shared__ double redu[9][PW];
    __shared__ double yshu[PW];
    __shared__ double wshu[PW];
    int lr = tid;
    double a = (lr<m)? A[(size_t)cc*QM2 + pc0 + lr] : 0.0;
    double vv[PW];
    #pragma unroll
    for (int j=0;j<PW;j++){
      double vj=0.0;
      if (lr<m){
        if (lr>j)       vj=A[(size_t)(pc0+j)*QM2 + pc0 + lr];
        else if (lr==j) vj=vhead[pc0+j];
      }
      vv[j]=vj;
    }
    #pragma unroll
    for (int j=0;j<PW;j++){
      double d=vv[j]*a;
      #pragma unroll
      for (int o=32;o>0;o>>=1) d+=__shfl_down(d,o);
      if (lane==0) redu[wid][j]=d;
    }
    __syncthreads();
    if (tid<PW){
      double y=0;
      #pragma unroll
      for (int t=0;t<9;t++) y+=redu[t][tid];
      yshu[tid]=y;
    }
    __syncthreads();
    if (tid<PW){
      double s=0;
      for (int t=0;t<=tid;t++) s+=T[t*PW+tid]*yshu[t];
      wshu[tid]=s;
    }
    __syncthreads();
    if (lr<m){
      double s=0;
      #pragma unroll
      for (int j=0;j<PW;j++) s+=vv[j]*wshu[j];
      A[(size_t)cc*QM2 + pc0 + lr]=a-s;
    }
    return;
  }

  __shared__ double redw[9][PW];
  __shared__ double rednorm[9];
  __shared__ double sh[3];
  __shared__ double wsh[PW];
  __shared__ double alphas[PW], betas[PW];
  __shared__ double VtVs[PW][PW];
  __shared__ double Tsh[PW][PW];
  __shared__ double redP[9][PW*PW];
  __shared__ double ysh2[PW][PW];
  __shared__ double wsh2[PW][PW];

  int m = QM2 - col0; if (m>QACT) m=QACT;
  bool on = tid < m;
  double x[PW];

  if (p>0){
    int pc0 = col0 - PW;
    const double* T = Tbufs + (size_t)(p-1)*PW*PW;
    int mp = QM2 - pc0; if (mp>QACT) mp=QACT;
    bool gA = on;
    bool gB = (tid>=560);
    int rowA = col0 + tid;
    int kB   = tid - 560;
    double vv[PW];
    #pragma unroll
    for (int j=0;j<PW;j++){
      double vj=0.0;
      if (gA){
        if (tid + PW < mp) vj = A[(size_t)(pc0+j)*QM2 + rowA];
      } else if (gB){
        if (kB>j)       vj=A[(size_t)(pc0+j)*QM2 + pc0 + kB];
        else if (kB==j) vj=vhead[pc0+j];
      }
      vv[j]=vj;
    }
    #pragma unroll
    for (int c=0;c<PW;c++){
      double a=0.0;
      if (gA)      a = A[(size_t)(col0+c)*QM2 + rowA];
      else if (gB) a = A[(size_t)(col0+c)*QM2 + pc0 + kB];
      x[c]=a;
    }
    #pragma unroll
    for (int c=0;c<PW;c++){
      #pragma unroll
      for (int j=0;j<PW;j++){
        double d=vv[j]*x[c];
        #pragma unroll
        for (int o=32;o>0;o>>=1) d+=__shfl_down(d,o);
        if (lane==0) redP[wid][c*PW+j]=d;
      }
    }
    __syncthreads();
    if (tid<PW*PW){
      double y=0;
      #pragma unroll
      for (int t=0;t<9;t++) y+=redP[t][tid];
      ysh2[tid>>4][tid&15]=y;
    }
    __syncthreads();
    if (tid<PW*PW){
      int c=tid>>4, jj=tid&15;
      double s=0;
      for (int t=0;t<=jj;t++) s+=T[t*PW+jj]*ysh2[c][t];
      wsh2[c][jj]=s;
    }
    __syncthreads();
    #pragma unroll
    for (int c=0;c<PW;c++){
      double s=0;
      #pragma unroll
      for (int j=0;j<PW;j++) s+=vv[j]*wsh2[c][j];
      x[c]-=s;
    }
    if (gB){
      #pragma unroll
      for (int c=0;c<PW;c++) A[(size_t)(col0+c)*QM2 + pc0 + kB] = x[c];
    }
    if (!on){
      #pragma unroll
      for (int c=0;c<PW;c++) x[c]=0.0;
    }
    __syncthreads();
  } else {
    // p==0: rows <512 from Atop region of AQ; rows 512..527 direct from Gbot
    #pragma unroll
    for (int j=0;j<PW;j++){
      double v=0.0;
      if (tid<512) v = A[(size_t)j*QM2 + tid];
      else if (tid<QACT){
        int rr=tid-512;
        v = (rr<=j)? Gbot[(size_t)j*512+rr] : 0.0;
      }
      x[j]=v;
    }
  }

  #pragma unroll
  for (int j=0;j<PW;j++){
    double v0 = (tid>=j && on)? x[j] : 0.0;
    double ps = v0*v0;
    #pragma unroll
    for (int o=32;o>0;o>>=1) ps += __shfl_down(ps,o);
    if (lane==0) rednorm[wid]=ps;
    if (tid==j) sh[0]=x[j];
    __syncthreads();
    if (tid==0){
      double s0=0;
      for (int t=0;t<9;t++) s0+=rednorm[t];
      double x1=sh[0];
      double nrm=sqrt(s0);
      double alpha=(x1>=0.0)?-nrm:nrm;     // LAPACK: R_cc = -sign(x1)*||x||
      double v1=x1-alpha;
      double vtv=s0-2.0*alpha*x1+alpha*alpha;
      double b=(vtv>0.0)?2.0/vtv:0.0;
      sh[1]=v1; sh[2]=b;
      alphas[j]=alpha; betas[j]=b;
      vhead[col0+j]=v1;
    }
    __syncthreads();
    if (tid==j) x[j]=sh[1];
    double b=sh[2];
    double v=(tid>=j && on)? x[j] : 0.0;
    #pragma unroll
    for (int t=0;t<PW;t++){
      if (t==j) continue;
      double pdot=v*x[t];
      #pragma unroll
      for (int o=32;o>0;o>>=1) pdot+=__shfl_down(pdot,o);
      if (lane==0) redw[wid][t]=pdot;
    }
    __syncthreads();
    if (tid<PW && tid!=j){
      double tot=0;
      #pragma unroll
      for (int t2=0;t2<9;t2++) tot+=redw[t2][tid];
      if (tid>j) wsh[tid]=b*tot;
      else       VtVs[tid][j]=tot;
    }
    __syncthreads();
    if (v!=0.0){
      #pragma unroll
      for (int t=j+1;t<PW;t++) x[t]-=wsh[t]*v;
    }
  }
  __syncthreads();
  if (tid<PW){
    int i=tid;
    Tsh[i][i]=betas[i];
    for (int j2=i+1;j2<PW;j2++){
      double z=0;
      for (int t=i;t<j2;t++) z+=Tsh[i][t]*VtVs[t][j2];
      Tsh[i][j2]=-betas[j2]*z;
    }
  }
  __syncthreads();
  for (int e=tid;e<PW*PW;e+=576){
    int i=e/PW, j2=e%PW;
    Tbufs[(size_t)p*PW*PW + e] = (j2>=i)? Tsh[i][j2] : 0.0;
  }
  if (on){
    #pragma unroll
    for (int j=0;j<PW;j++)
      A[(size_t)(col0+j)*QM2 + col0 + tid] = (tid==j)? alphas[j] : x[j];
  }
}

// fused: R column norms + backward solve R x = m_obs + diffusion + error (R in AQ, lda QM2)
__global__ __launch_bounds__(512) void k_rpost(const double* Aq, const double* mobs,
                                               double* scal, float* out){
  __shared__ double b[DDIM];
  __shared__ double xs[DDIM];
  __shared__ double D[NB][NB+1];
  __shared__ double red[DDIM];
  __shared__ double g1sh[DDIM];
  int tid=threadIdx.x;
  {
    double s=0;
    for (int r=0;r<=tid;r++){ double v=Aq[(size_t)tid*QM2 + r]; s+=v*v; }
    g1sh[tid]=s;
  }
  b[tid]=mobs[tid];
  __syncthreads();
  for (int p=7;p>=0;p--){
    int b0=p*NB;
    for (int e=tid;e<NB*NB;e+=512){ int i=e&63, j2=e>>6; D[i][j2]=Aq[(size_t)(b0+j2)*QM2 + b0+i]; }
    __syncthreads();
    if (tid<64){
      double bi=b[b0+tid];
      for (int k=NB-1;k>=0;k--){
        double bk=__shfl(bi,k);
        double xk=bk/D[k][k];
        if (tid<k) bi-=D[tid][k]*xk;
        if (tid==k) bi=xk;
      }
      xs[b0+tid]=bi;
    }
    __syncthreads();
    if (tid<b0){
      double s=0;
      #pragma unroll 8
      for (int j2=0;j2<NB;j2++) s+=Aq[(size_t)(b0+j2)*QM2 + tid]*xs[b0+j2];
      b[tid]-=s;
    }
    __syncthreads();
  }
  red[tid]=xs[tid]*xs[tid]; __syncthreads();
  for (int s=256;s>0;s>>=1){ if (tid<s) red[tid]+=red[tid+s]; __syncthreads(); }
  double diff=sqrt(red[0]/(double)DDIM);
  if (tid==0){ scal[10]=diff; out[OUT_DIFF]=(float)diff; }
  out[OUT_ERR+tid]=(float)(diff*sqrt(fmax(g1sh[tid],0.0)));
}

// X = a @ (p_inv[:,None]*l0)
__global__ void k_X(const float* a, const float* l0, const double* scal, float* X){
  int idx=blockIdx.x*blockDim.x+threadIdx.x;
  if (idx>=KDIM*KDIM) return;
  double pv[5];
  #pragma unroll
  for (int t=0;t<5;t++) pv[t]=scal[5+t];
  int r=idx/KDIM, c=idx%KDIM;
  int j=r/5;
  const float* arow = a + (size_t)r*KDIM + 5*j;
  double acc=0;
  #pragma unroll
  for (int l=0;l<5;l++)
    acc += (double)arow[l]*pv[l]*(double)l0[(size_t)(5*j+l)*KDIM+c];
  X[idx]=(float)acc;
}

// ---- 32x32-tile GEMM, 2x2 per thread, fp64 accumulate ----
template<typename TA,int ATR,typename TB,int BTR,int MODE>
__global__ __launch_bounds__(256) void gemm32(const TA* __restrict__ A,int lda,
                                              const TB* __restrict__ B,int ldb,
                                              void* __restrict__ Cv,int ldc,
                                              int K,int kmode){
  __shared__ double As[32][33];
  __shared__ double Bs[32][33];
  int tid=threadIdx.x, tx=tid&15, ty=tid>>4;
  int n0=blockIdx.x*32, m0=blockIdx.y*32;
  int ks=0, ke=K;
  if (kmode==1) ks=n0;
  else if (kmode==2) ke=min(K,n0+32);
  else if (kmode==3) ke=min(K,m0+32);
  else if (kmode==4) ks=m0;
  double acc[2][2]={};
  for (int k0=ks;k0<ke;k0+=32){
    if (ATR){
      for (int e=tid;e<32*32;e+=256){int k=e>>5,mm=e&31; As[k][mm]=(double)A[(size_t)(k0+k)*lda+m0+mm];}
    } else {
      for (int e=tid;e<32*32;e+=256){int mm=e>>5,k=e&31; As[k][mm]=(double)A[(size_t)(m0+mm)*lda+k0+k];}
    }
    if (BTR){
      for (int e=tid;e<32*32;e+=256){int nn=e>>5,k=e&31; Bs[k][nn]=(double)B[(size_t)(n0+nn)*ldb+k0+k];}
    } else {
      for (int e=tid;e<32*32;e+=256){int k=e>>5,nn=e&31; Bs[k][nn]=(double)B[(size_t)(k0+k)*ldb+n0+nn];}
    }
    __syncthreads();
    #pragma unroll
    for (int t=0;t<32;t++){
      double av[2],bv[2];
      #pragma unroll
      for (int i=0;i<2;i++){av[i]=As[t][ty+16*i];bv[i]=Bs[t][tx+16*i];}
      #pragma unroll
      for (int i=0;i<2;i++)
        #pragma unroll
        for (int j=0;j<2;j++) acc[i][j]+=av[i]*bv[j];
    }
    __syncthreads();
  }
  #pragma unroll
  for (int i=0;i<2;i++){
    #pragma unroll
    for (int j=0;j<2;j++){
      size_t idx=(size_t)(m0+ty+16*i)*ldc+n0+tx+16*j;
      if (MODE==0) ((double*)Cv)[idx]=acc[i][j];
      else if (MODE==1) ((double*)Cv)[idx]-=acc[i][j];
      else ((float*)Cv)[idx]=(float)acc[i][j];
    }
  }
}

// G (lower tiles) = X X^T (band-limited) + fused diffusion^2 * kron(I, L1 L1^T)
// 1-D triangular grid, longest-K first; float4 staging loads (K-chunk 16)
__global__ __launch_bounds__(256) void syrk_lower(const float* __restrict__ X, const float* __restrict__ q,
                                                  const double* __restrict__ scal,
                                                  double* __restrict__ G, int n){
  int t = blockIdx.x;
  int u = (int)((sqrtf(8.0f*(float)t+1.0f)+1.0f)*0.5f);
  while ((u*(u-1))/2 > t) u--;
  while ((u*(u+1))/2 <= t) u++;
  int s = (KDIM/64) - u;
  int r = s + (t - (u*(u-1))/2);
  int S0=s*64, R0=r*64;
  __shared__ double As[16][65];
  __shared__ double Bs[16][65];
  int tid=threadIdx.x, tx=tid&15, ty=tid>>4;
  int kend=min(n, S0+80);
  double acc[4][4]={};
  int mm=tid>>2, f=tid&3;
  for (int k0=0;k0<kend;k0+=16){
    {
      float4 xa = *(const float4*)(X + (size_t)(R0+mm)*n + k0 + 4*f);
      float4 xb = *(const float4*)(X + (size_t)(S0+mm)*n + k0 + 4*f);
      As[4*f+0][mm]=(double)xa.x; As[4*f+1][mm]=(double)xa.y;
      As[4*f+2][mm]=(double)xa.z; As[4*f+3][mm]=(double)xa.w;
      Bs[4*f+0][mm]=(double)xb.x; Bs[4*f+1][mm]=(double)xb.y;
      Bs[4*f+2][mm]=(double)xb.z; Bs[4*f+3][mm]=(double)xb.w;
    }
    __syncthreads();
    #pragma unroll
    for (int t2=0;t2<16;t2++){
      double av[4],bv[4];
      #pragma unroll
      for (int i=0;i<4;i++){av[i]=As[t2][ty+16*i];bv[i]=Bs[t2][tx+16*i];}
      #pragma unroll
      for (int i=0;i<4;i++)
        #pragma unroll
        for (int j=0;j<4;j++) acc[i][j]+=av[i]*bv[j];
    }
    __syncthreads();
  }
  double dd = scal[10]*scal[10];
  #pragma unroll
  for (int i=0;i<4;i++)
    #pragma unroll
    for (int j=0;j<4;j++){
      int rr=R0+ty+16*i, c=S0+tx+16*j;
      double v=acc[i][j];
      if (c<=rr && (rr/5)==(c/5)){
        double qq=0;
        #pragma unroll
        for (int k=0;k<5;k++) qq += (double)q[(size_t)(rr%5)*KDIM+k]*(double)q[(size_t)(c%5)*KDIM+k];
        v += dd*qq;
      }
      G[(size_t)rr*n+c]=v;
    }
}

// ---- blocked Cholesky ----
__global__ __launch_bounds__(256) void chol_diag(double* A, int n, int k0){
  __shared__ double P[NB][NB+1];
  int tid=threadIdx.x;
  for (int e=tid;e<NB*NB;e+=256){int r=e>>6,c=e&63;P[r][c]=A[(size_t)(k0+r)*n+k0+c];}
  int tx=tid&15, ty=tid>>4;
  __syncthreads();
  for (int j=0;j<NB;j++){
    double pj=P[j][j];
    __syncthreads();
    double rpj=1.0/sqrt(fmax(pj,1e-280));
    if (tid>j && tid<NB) P[tid][j]*=rpj;
    if (tid==j) P[j][j]=sqrt(fmax(pj,1e-280));
    __syncthreads();
    #pragma unroll
    for (int a2=0;a2<4;a2++){
      int r=ty+16*a2;
      double lrj=P[r][j];
      #pragma unroll
      for (int b2=0;b2<4;b2++){
        int c=tx+16*b2;
        if (r>j && c>j && c<=r) P[r][c]-=lrj*P[c][j];
      }
    }
    __syncthreads();
  }
  for (int e=tid;e<NB*NB;e+=256){int r=e>>6,c=e&63;A[(size_t)(k0+r)*n+k0+c]=P[r][c];}
}

// ONE launch per elimination step: each block locally re-solves its two panel
// tiles vs L_D (forward substitution — identical to trsm output),
// updates trailing tile (r,s); tile 0 fuses next-diag factorization.
__global__ __launch_bounds__(256) void chol_step(double* __restrict__ A, int n, int k0){
  __shared__ double Ls[NB][NB+1];   // L_D; reused as P by tile 0
  __shared__ double rec[NB];
  __shared__ double As[16][65];
  __shared__ double Bs[16][65];
  int ts0=k0+NB;
  int t=blockIdx.x;
  int r=(int)((sqrtf(8.0f*(float)t+1.0f)-1.0f)*0.5f);
  while ((r*(r+1))/2 > t) r--;
  while (((r+1)*(r+2))/2 <= t) r++;
  int s=t-(r*(r+1))/2;
  int R0=ts0+r*NB, S0=ts0+s*NB;
  int tid=threadIdx.x, tx=tid&15, ty=tid>>4;
  for (int e=tid;e<NB*NB;e+=256){int rr=e>>6,c=e&63;Ls[rr][c]=A[(size_t)(k0+rr)*n+k0+c];}
  __syncthreads();
  if (tid<NB) rec[tid]=1.0/Ls[tid][tid];
  __syncthreads();
  double ar[NB];
  bool solver = (tid<64) || (tid<128 && s!=r);
  int srow = (tid<64)? (R0+tid) : (S0+(tid-64));
  if (solver){
    #pragma unroll
    for (int c=0;c<NB;c++) ar[c]=A[(size_t)srow*n + k0 + c];
    #pragma unroll
    for (int j=0;j<NB;j++){
      double sv=ar[j];
      #pragma unroll
      for (int t2=0;t2<j;t2++) sv-=ar[t2]*Ls[j][t2];
      ar[j]=sv*rec[j];
    }
  }
  double acc[4][4]={};
  #pragma unroll
  for (int c4=0;c4<4;c4++){
    __syncthreads();
    if (tid<64){
      #pragma unroll
      for (int k=0;k<16;k++) As[k][tid]=ar[c4*16+k];
      if (s==r){
        #pragma unroll
        for (int k=0;k<16;k++) Bs[k][tid]=ar[c4*16+k];
      }
    } else if (tid<128 && s!=r){
      #pragma unroll
      for (int k=0;k<16;k++) Bs[k][tid-64]=ar[c4*16+k];
    }
    __syncthreads();
    #pragma unroll
    for (int tt=0;tt<16;tt++){
      double av[4],bv[4];
      #pragma unroll
      for (int i=0;i<4;i++){av[i]=As[tt][ty+16*i];bv[i]=Bs[tt][tx+16*i];}
      #pragma unroll
      for (int i=0;i<4;i++)
        #pragma unroll
        for (int j=0;j<4;j++) acc[i][j]+=av[i]*bv[j];
    }
  }
  __syncthreads();
  if (t!=0){
    #pragma unroll
    for (int i=0;i<4;i++)
      #pragma unroll
      for (int j=0;j<4;j++)
        A[(size_t)(R0+ty+16*i)*n+S0+tx+16*j]-=acc[i][j];
    return;
  }
  double (*P)[NB+1] = Ls;
  #pragma unroll
  for (int i=0;i<4;i++)
    #pragma unroll
    for (int j=0;j<4;j++)
      P[ty+16*i][tx+16*j] = A[(size_t)(ts0+ty+16*i)*n+ts0+tx+16*j] - acc[i][j];
  __syncthreads();
  for (int j=0;j<NB;j++){
    double pj=P[j][j];
    __syncthreads();
    double rpj=1.0/sqrt(fmax(pj,1e-280));
    if (tid>j && tid<NB) P[tid][j]*=rpj;
    if (tid==j) P[j][j]=sqrt(fmax(pj,1e-280));
    __syncthreads();
    #pragma unroll
    for (int a2=0;a2<4;a2++){
      int r2=ty+16*a2;
      double lrj=P[r2][j];
      #pragma unroll
      for (int b2=0;b2<4;b2++){
        int c=tx+16*b2;
        if (r2>j && c>j && c<=r2) P[r2][c]-=lrj*P[c][j];
      }
    }
    __syncthreads();
  }
  for (int e=tid;e<NB*NB;e+=256){int r2=e>>6,c=e&63;A[(size_t)(ts0+r2)*n+ts0+c]=P[r2][c];}
}

// final sweep: trsm ALL raw panels vs their factored diagonals in ONE launch.
__global__ __launch_bounds__(256) void chol_sweep(double* A, int n){
  __shared__ double Ls[NB][NB+1];
  __shared__ double St[NB][NB+1];
  __shared__ double rec[NB];
  int k0=blockIdx.y*NB;
  int base=k0+NB+blockIdx.x*256;
  if (base>=n) return;
  int tid=threadIdx.x;
  for (int e=tid;e<NB*NB;e+=256){int r2=e>>6,c=e&63;Ls[r2][c]=A[(size_t)(k0+r2)*n+k0+c];}
  __syncthreads();
  if (tid<NB) rec[tid]=1.0/Ls[tid][tid];
  int myrow=base+tid, mychunk=tid>>6, lrow=tid&63;
  double ar[NB];
  for (int ch=0;ch<4;ch++){
    int r0=base+ch*64;
    for (int e=tid;e<NB*NB;e+=256){
      int r2=e>>6,c=e&63;
      if (r0+r2<n) St[r2][c]=A[(size_t)(r0+r2)*n+k0+c];
    }
    __syncthreads();
    if (mychunk==ch && myrow<n){
      #pragma unroll
      for (int c=0;c<NB;c++) ar[c]=St[lrow][c];
    }
    __syncthreads();
  }
  if (myrow<n){
    #pragma unroll
    for (int j=0;j<NB;j++){
      double s2=ar[j];
      #pragma unroll
      for (int t2=0;t2<j;t2++) s2-=ar[t2]*Ls[j][t2];
      ar[j]=s2*rec[j];
    }
  }
  for (int ch=0;ch<4;ch++){
    int r0=base+ch*64;
    if (mychunk==ch && myrow<n){
      #pragma unroll
      for (int c=0;c<NB;c++) St[lrow][c]=ar[c];
    }
    __syncthreads();
    for (int e=tid;e<NB*NB;e+=256){
      int r2=e>>6,c=e&63;
      if (r0+r2<n) A[(size_t)(r0+r2)*n+k0+c]=St[r2][c];
    }
    __syncthreads();
  }
}

// l_ext (f32) = p[:,None] * chol(G2), zero strict upper
__global__ void k_extract(const double* G2, const double* scal, float* lext){
  int idx=blockIdx.x*blockDim.x+threadIdx.x;
  if (idx>=KDIM*KDIM) return;
  int r=idx/KDIM, c=idx%KDIM;
  double v = (c<=r)? scal[r%5]*G2[idx] : 0.0;
  lext[idx]=(float)v;
}

// ---- explicit blocked inverse of lower-triangular L (512) ----
__global__ __launch_bounds__(256) void trinv_diag(const double* S, double* Linv){
  __shared__ double Ls[NB][NB+1];
  __shared__ double Ti[NB][NB+1];
  int jb=blockIdx.x, tid=threadIdx.x;
  for (int e=tid; e<DDIM*NB; e+=256){
    int r=e/NB, c=e%NB;
    Linv[(size_t)r*DDIM + jb*NB + c]=0.0;
  }
  for (int e=tid;e<NB*NB;e+=256){int r=e>>6,c=e&63; Ls[r][c]=S[(size_t)(jb*NB+r)*DDIM + jb*NB+c];}
  __syncthreads();
  if (tid<NB){
    int c=tid;
    for (int r=c;r<NB;r++){
      double s=(r==c)?1.0:0.0;
      for (int t=c;t<r;t++) s-=Ls[r][t]*Ti[t][c];
      Ti[r][c]=s/Ls[r][r];
    }
    for (int r=0;r<c;r++) Ti[r][c]=0.0;
  }
  __syncthreads();
  for (int e=tid;e<NB*NB;e+=256){int r=e>>6,c=e&63; Linv[(size_t)(jb*NB+r)*DDIM + jb*NB+c]=Ti[r][c];}
}

__global__ __launch_bounds__(256) void trinv_step(const double* S, double* Linv, int d){
  __shared__ double As[16][65];
  __shared__ double Bs[16][65];
  __shared__ double Ps[NB][NB+1];
  int jb=blockIdx.x, ib=jb+d;
  int tid=threadIdx.x, tx=tid&15, ty=tid>>4;
  double acc[4][4]={};
  int kstart=jb*NB, kend=ib*NB;
  for (int k0=kstart;k0<kend;k0+=16){
    for (int e=tid;e<64*16;e+=256){int mm=e>>4,k=e&15; As[k][mm]=S[(size_t)(ib*NB+mm)*DDIM + k0+k];}
    for (int e=tid;e<16*64;e+=256){int k=e>>6,nn=e&63; Bs[k][nn]=Linv[(size_t)(k0+k)*DDIM + jb*NB+nn];}
    __syncthreads();
    #pragma unroll
    for (int t=0;t<16;t++){
      double av[4],bv[4];
      #pragma unroll
      for (int i=0;i<4;i++){av[i]=As[t][ty+16*i];bv[i]=Bs[t][tx+16*i];}
      #pragma unroll
      for (int i=0;i<4;i++)
        #pragma unroll
        for (int j=0;j<4;j++) acc[i][j]+=av[i]*bv[j];
    }
    __syncthreads();
  }
  #pragma unroll
  for (int i=0;i<4;i++)
    #pragma unroll
    for (int j=0;j<4;j++) Ps[ty+16*i][tx+16*j]=acc[i][j];
  double o[4][4]={};
  __syncthreads();
  for (int k0=0;k0<NB;k0+=16){
    for (int e=tid;e<64*16;e+=256){int mm=e>>4,k=e&15; As[k][mm]=Linv[(size_t)(ib*NB+mm)*DDIM + ib*NB+k0+k];}
    __syncthreads();
    #pragma unroll
    for (int t=0;t<16;t++){
      double av[4],bv[4];
      #pragma unroll
      for (int i=0;i<4;i++){av[i]=As[t][ty+16*i];bv[i]=Ps[k0+t][tx+16*i];}
      #pragma unroll
      for (int i=0;i<4;i++)
        #pragma unroll
        for (int j=0;j<4;j++) o[i][j]+=av[i]*bv[j];
    }
    __syncthreads();
  }
  #pragma unroll
  for (int i=0;i<4;i++)
    #pragma unroll
    for (int j=0;j<4;j++)
      Linv[(size_t)(ib*NB+ty+16*i)*DDIM + jb*NB+tx+16*j] = -o[i][j];
}

// m_cor = m_ext - Z^T @ m_obs; also u
__global__ void k_mcor(const double* Z, const double* mobs, const double* mext, float* out){
  __shared__ double mo[DDIM];
  for (int s=threadIdx.x;s<DDIM;s+=256) mo[s]=mobs[s];
  __syncthreads();
  int r=blockIdx.x*256+threadIdx.x;
  if (r>=KDIM) return;
  double acc=0;
  for (int s=0;s<DDIM;s++) acc += Z[(size_t)s*KDIM+r]*mo[s];
  double mc = mext[r]-acc;
  out[r]=(float)mc;
  if (r%5==0) out[OUT_U + r/5]=(float)mc;
}

// l_cor = l_ext - Z^T @ l_obs_ns (64x64 tiles); float4 staging for lobs
__global__ __launch_bounds__(256) void k_lcor(const double* __restrict__ Z, const float* __restrict__ lobs,
                                              const float* __restrict__ lext, float* __restrict__ out){
  __shared__ double As[16][65];
  __shared__ double Bs[16][65];
  int tid=threadIdx.x, tx=tid&15, ty=tid>>4;
  int n0=blockIdx.x*64, m0=blockIdx.y*64;
  double acc[4][4]={};
  int kk=tid>>4, f=tid&15;
  for (int k0=0;k0<DDIM;k0+=16){
    for (int e=tid;e<16*64;e+=256){int k=e>>6,mm=e&63; As[k][mm]=Z[(size_t)(k0+k)*KDIM+m0+mm];}
    {
      float4 xb = *(const float4*)(lobs + (size_t)(k0+kk)*KDIM + n0 + 4*f);
      Bs[kk][4*f+0]=(double)xb.x; Bs[kk][4*f+1]=(double)xb.y;
      Bs[kk][4*f+2]=(double)xb.z; Bs[kk][4*f+3]=(double)xb.w;
    }
    __syncthreads();
    #pragma unroll
    for (int t=0;t<16;t++){
      double av[4],bv[4];
      #pragma unroll
      for (int i=0;i<4;i++){av[i]=As[t][ty+16*i];bv[i]=Bs[t][tx+16*i];}
      #pragma unroll
      for (int i=0;i<4;i++)
        #pragma unroll
        for (int j=0;j<4;j++) acc[i][j]+=av[i]*bv[j];
    }
    __syncthreads();
  }
  #pragma unroll
  for (int i=0;i<4;i++)
    #pragma unroll
    for (int j=0;j<4;j++){
      size_t idx=(size_t)(m0+ty+16*i)*KDIM+n0+tx+16*j;
      out[OUT_LCOR+idx]=(float)((double)lext[idx]-acc[i][j]);
    }
}

extern "C" void kernel_launch(void* const* d_in, const int* in_sizes, int n_in,
                              void* d_out, int out_size, void* d_ws, size_t ws_size,
                              hipStream_t stream) {
  const float* m0  = (const float*)d_in[0];
  const float* l0  = (const float*)d_in[1];
  const float* H   = (const float*)d_in[2];
  const float* bias= (const float*)d_in[3];
  const float* dt  = (const float*)d_in[4];
  const float* a   = (const float*)d_in[5];
  const float* q   = (const float*)d_in[6];
  float* out = (float*)d_out;

  char* w=(char*)d_ws;
  auto alloc=[&](size_t bytes)->char*{ char* p=w; w += ((bytes+255)/256)*256; return p; };
  double* scal  =(double*)alloc(16*8);
  double* mext  =(double*)alloc((size_t)KDIM*8);
  double* mobs  =(double*)alloc((size_t)DDIM*8);
  double* vheadA=(double*)alloc((size_t)QN*8);
  double* Tbufs =(double*)alloc((size_t)(QN/PW)*PW*PW*8);  // per-step T factors
  double* AQ    =(double*)alloc((size_t)QM2*QN*8);    // compressed QR matrix (1024x512 col-major)
  double* S     =(double*)alloc((size_t)DDIM*DDIM*8); // innovation Gram + chol
  double* G2    =(double*)alloc((size_t)KDIM*KDIM*8); // big Gram -> chol; region reused
  float*  LOBS  =(float*) alloc((size_t)DDIM*KDIM*4);
  float*  X     =(float*) alloc((size_t)KDIM*KDIM*4); // X; later l_ext
  float*  LEXT  = X;
  // G2 region used as scratch BEFORE syrk_lower (QR compression):
  double* Abot  = G2;                                  // 2048x512 col-major
  double* Gbot  = Abot + (size_t)2048*512;             // 512x512
  // after k_extract, G2 region reused again:
  double* Linv  = G2;                                  // 512x512
  double* C2    = Linv + (size_t)DDIM*DDIM;            // 512x2560
  double* Y     = C2   + (size_t)DDIM*KDIM;            // 512x2560
  double* Z     = Y    + (size_t)DDIM*KDIM;            // 512x2560

  // Cholesky: diag0 + 1 fused launch per step + one parallel panel sweep
  auto chol_full=[&](double* M, int n){
    chol_diag<<<1,256,0,stream>>>(M, n, 0);
    for (int k0=0;k0+NB<n;k0+=NB){
      int T = (n-k0-NB)/NB;
      chol_step<<<T*(T+1)/2,256,0,stream>>>(M,n,k0);
    }
    dim3 g((n-NB+255)/256, n/NB-1);
    chol_sweep<<<g,256,0,stream>>>(M,n);
  };

  // ---- setup + extrapolate mean + observe (k_setup folded in) ----
  k_mext_mobs<<<DDIM,256,0,stream>>>(a, m0, H, bias, dt, scal, mext, mobs);

  // ---- first QR, compressed: A'' = [A_top(512); chol(A_bot^T A_bot)^T] (R identical, signs incl.)
  k_A2<<<(QN*QM+255)/256,256,0,stream>>>(H, q, scal, AQ, Abot);
  gemm32<double,0,double,1,0><<<dim3(16,16),256,0,stream>>>(Abot,2048, Abot,2048, Gbot,512, 2048, 0);
  chol_full(Gbot, 512);
  for (int p=0;p<QN/PW;p++){
    int grid;
    if (p==0) grid = 1 + (496*512 + 575)/576;   // block0=panel; rest copy B cols 16..511
    else      grid = 1 + (QN - (p+1)*PW);
    qr_step<<<grid,576,0,stream>>>(AQ, vheadA, Tbufs, Gbot, p);
  }
  k_rpost<<<1,512,0,stream>>>(AQ, mobs, scal, out);

  // ---- extrapolated covariance sqrt via Gram + Cholesky ----
  k_X<<<(KDIM*KDIM+255)/256,256,0,stream>>>(a, l0, scal, X);
  syrk_lower<<<(KDIM/64)*((KDIM/64)+1)/2,256,0,stream>>>(X, q, scal, G2, KDIM);
  chol_full(G2, KDIM);
  k_extract<<<(KDIM*KDIM+255)/256,256,0,stream>>>(G2, scal, LEXT);  // G2 dead afterwards

  // ---- correction ----
  gemm32<float,0,float,0,2><<<dim3(KDIM/32,DDIM/32),256,0,stream>>>(H,KDIM, LEXT,KDIM, LOBS,KDIM, KDIM, 1);
  gemm32<float,0,float,1,0><<<dim3(DDIM/32,DDIM/32),256,0,stream>>>(LOBS,KDIM, LOBS,KDIM, S,DDIM, KDIM, 0);
  chol_full(S, DDIM);
  trinv_diag<<<8,256,0,stream>>>(S, Linv);
  for (int d=1;d<8;d++)
    trinv_step<<<8-d,256,0,stream>>>(S, Linv, d);
  gemm32<float,0,float,1,0><<<dim3(KDIM/32,DDIM/32),256,0,stream>>>(LOBS,KDIM, LEXT,KDIM, C2,KDIM, KDIM, 2);
  gemm32<double,0,double,0,0><<<dim3(KDIM/32,DDIM/32),256,0,stream>>>(Linv,DDIM, C2,KDIM, Y,KDIM, DDIM, 3);
  gemm32<double,1,double,0,0><<<dim3(KDIM/32,DDIM/32),256,0,stream>>>(Linv,DDIM, Y,KDIM, Z,KDIM, DDIM, 4);

  k_mcor<<<(KDIM+255)/256,256,0,stream>>>(Z, mobs, mext, out);
  k_lcor<<<dim3(KDIM/64,KDIM/64),256,0,stream>>>(Z, LOBS, LEXT, out);
}